// Round 5
// baseline (783.533 us; speedup 1.0000x reference)
//
#include <hip/hip_runtime.h>
#include <hip/hip_bf16.h>

#define NN   100000
#define EE   3200000
#define HH   32
#define BB   128
#define KMAX 96
#define NB   1024
#define SPAN 98          // bucket b covers dst in [b*98, b*98+98)
#define EBLK 256         // edge-chunk blocks
#define CHUNK 12500      // EE / EBLK exactly

// ws layout (bytes), non-overlapping, < 61 MB total
static constexpr size_t Q0_OFF     = 0;           // N*16 bf16 = 3.2 MB (L2-resident half)
static constexpr size_t Q1_OFF     = 3200000;     // N*16 bf16 = 3.2 MB
static constexpr size_t AGG_OFF    = 6400000;     // N*32 f32 = 12.8 MB
static constexpr size_t H_OFF      = 19200000;    // N*32 f32 = 12.8 MB
static constexpr size_t EPACK_OFF  = 32000000;    // EE int = 12.8 MB
static constexpr size_t SRC_OFF    = 44800000;    // EE int = 12.8 MB compact csr
static constexpr size_t OFF_OFF    = 57600000;    // (N+1) int
static constexpr size_t HIST_OFF   = 58100000;    // EBLK*NB int = 1 MB
static constexpr size_t START_OFF  = 59200000;    // EBLK*NB int = 1 MB
static constexpr size_t BBASE_OFF  = 60300000;    // (NB+1) int
static constexpr size_t TOT_OFF    = 60310000;    // NB int
static constexpr size_t STATS_OFF  = 60320000;    // 64 f32
static constexpr size_t BNAB_OFF   = 60320256;    // 64 f32
static constexpr size_t POOLED_OFF = 60320512;    // B*32 f32
static constexpr size_t PCNT_OFF   = 60336896;    // B f32
static constexpr size_t ZERO_OFF   = POOLED_OFF;
static constexpr size_t ZERO_BYTES = 16896;

// ---- K1: per-block LDS histogram of dst buckets
__global__ __launch_bounds__(256) void hist_kernel(const int* __restrict__ ei,
                                                   int* __restrict__ hist) {
    __shared__ int lh[NB];
    int tid = threadIdx.x, blk = blockIdx.x;
    for (int i = tid; i < NB; i += 256) lh[i] = 0;
    __syncthreads();
    int e0 = blk * CHUNK;
    for (int e = e0 + tid; e < e0 + CHUNK; e += 256) {
        int d = ei[EE + e];
        atomicAdd(&lh[d / SPAN], 1);
    }
    __syncthreads();
    for (int i = tid; i < NB; i += 256) hist[blk * NB + i] = lh[i];
}

// ---- K2a: bucket totals
__global__ __launch_bounds__(64) void totals_kernel(const int* __restrict__ hist,
                                                    int* __restrict__ tot) {
    int b = blockIdx.x * 64 + threadIdx.x;
    int s = 0;
    for (int blk = 0; blk < EBLK; blk++) s += hist[blk * NB + b];
    tot[b] = s;
}

// ---- K2b: exclusive scan of 1024 totals
__global__ __launch_bounds__(1024) void scan_kernel(const int* __restrict__ tot,
                                                    int* __restrict__ bbase) {
    __shared__ int sm[NB];
    int t = threadIdx.x;
    int mine = tot[t];
    sm[t] = mine;
    __syncthreads();
    for (int off = 1; off < NB; off <<= 1) {
        int v = (t >= off) ? sm[t - off] : 0;
        __syncthreads();
        sm[t] += v;
        __syncthreads();
    }
    bbase[t] = sm[t] - mine;
    if (t == NB - 1) bbase[NB] = sm[t];
}

// ---- K2c: per-(block,bucket) start offsets
__global__ __launch_bounds__(128) void starts_kernel(const int* __restrict__ hist,
                                                     const int* __restrict__ bbase,
                                                     int* __restrict__ start) {
    int b = blockIdx.x * 128 + threadIdx.x;
    int run = bbase[b];
    for (int blk = 0; blk < EBLK; blk++) {
        start[blk * NB + b] = run;
        run += hist[blk * NB + b];
    }
}

// ---- K3: scatter packed (src | dstoff<<20) into bucket-grouped array (4 B/edge)
__global__ __launch_bounds__(256) void scatter_kernel(const int* __restrict__ ei,
                                                      const int* __restrict__ start,
                                                      int* __restrict__ epack) {
    __shared__ int loff[NB];
    int tid = threadIdx.x, blk = blockIdx.x;
    for (int i = tid; i < NB; i += 256) loff[i] = start[blk * NB + i];
    __syncthreads();
    int e0 = blk * CHUNK;
    for (int e = e0 + tid; e < e0 + CHUNK; e += 256) {
        int s = ei[e];
        int d = ei[EE + e];
        int b = d / SPAN;
        int slot = atomicAdd(&loff[b], 1);
        epack[slot] = s | ((d - b * SPAN) << 20);
    }
}

// ---- K4: per-bucket compact CSR build in LDS; exact offsets + dense src writeout
__global__ __launch_bounds__(256) void csr_compact_kernel(const int* __restrict__ epack,
                                                          const int* __restrict__ bbase,
                                                          int* __restrict__ off,
                                                          int* __restrict__ srcs) {
    __shared__ int lcnt[SPAN];
    __shared__ int lbase[SPAN + 1];
    __shared__ int lcsr[SPAN * KMAX];   // 37632 B
    int b = blockIdx.x;
    int tid = threadIdx.x;
    int base = b * SPAN;
    int span_here = NN - base;
    if (span_here <= 0) return;
    if (span_here > SPAN) span_here = SPAN;
    for (int i = tid; i < SPAN; i += 256) lcnt[i] = 0;
    __syncthreads();
    int p0 = bbase[b], p1 = bbase[b + 1];
    for (int i = p0 + tid; i < p1; i += 256) {
        int w = epack[i];
        int ld = w >> 20;
        int slot = atomicAdd(&lcnt[ld], 1);
        if (slot < KMAX) lcsr[ld * KMAX + slot] = w & 0xFFFFF;
    }
    __syncthreads();
    if (tid == 0) {
        int run = 0;
        for (int i = 0; i < span_here; i++) {
            lbase[i] = run;
            int c = lcnt[i]; if (c > KMAX) c = KMAX;
            run += c;
        }
        lbase[span_here] = run;
    }
    __syncthreads();
    for (int i = tid; i < span_here; i += 256) off[base + i] = p0 + lbase[i];
    if (base <= NN && NN < base + SPAN && tid == 0) off[NN] = p0 + lbase[span_here];
    int m = lbase[span_here];
    for (int j = tid; j < m; j += 256) {
        int lo = 0, hi = span_here - 1;
        while (lo < hi) {
            int mid = (lo + hi + 1) >> 1;
            if (lbase[mid] <= j) lo = mid; else hi = mid - 1;
        }
        srcs[p0 + j] = lcsr[lo * KMAX + (j - lbase[lo])];
    }
}

__device__ __forceinline__ unsigned bf16rn(float f) {
    unsigned b = __float_as_uint(f);
    return (b + 0x7fffu + ((b >> 16) & 1u)) >> 16;   // RNE
}

// ---- projection: q0/q1 (bf16 halves, 32 B rows) = h @ w1. FIN==32 folds prev BN.
template <int FIN>
__global__ __launch_bounds__(256) void proj_kernel(const float* __restrict__ hin,
                                                   const float* __restrict__ w1,
                                                   const float* __restrict__ bnab,
                                                   uint4* __restrict__ q0,
                                                   uint4* __restrict__ q1,
                                                   float* __restrict__ stats) {
    int tid = threadIdx.x;
    if (blockIdx.x == 0 && tid < 64) stats[tid] = 0.f;
    int n = blockIdx.x * 256 + tid;
    if (n >= NN) return;
    float acc[32];
#pragma unroll
    for (int c = 0; c < 32; c++) acc[c] = 0.f;
    const float4* h4 = (const float4*)(hin + (size_t)n * FIN);
    for (int jj = 0; jj < FIN; jj += 32) {
        float hv[32];
#pragma unroll
        for (int k = 0; k < 8; k++) {
            float4 v = h4[jj / 4 + k];
            hv[4 * k] = v.x; hv[4 * k + 1] = v.y; hv[4 * k + 2] = v.z; hv[4 * k + 3] = v.w;
        }
        if constexpr (FIN == 32) {
#pragma unroll
            for (int j = 0; j < 32; j++) hv[j] = fmaf(hv[j], bnab[j], bnab[32 + j]);
        }
#pragma unroll 4
        for (int j = 0; j < 32; j++) {
            float hvj = hv[j];
            const float* wrow = w1 + (size_t)(jj + j) * 32;
#pragma unroll
            for (int c = 0; c < 32; c++) acc[c] = fmaf(hvj, wrow[c], acc[c]);
        }
    }
    uint4 u[4];
#pragma unroll
    for (int k = 0; k < 4; k++) {
        u[k].x = bf16rn(acc[8*k+0]) | (bf16rn(acc[8*k+1]) << 16);
        u[k].y = bf16rn(acc[8*k+2]) | (bf16rn(acc[8*k+3]) << 16);
        u[k].z = bf16rn(acc[8*k+4]) | (bf16rn(acc[8*k+5]) << 16);
        u[k].w = bf16rn(acc[8*k+6]) | (bf16rn(acc[8*k+7]) << 16);
    }
    q0[(size_t)n * 2]     = u[0];
    q0[(size_t)n * 2 + 1] = u[1];
    q1[(size_t)n * 2]     = u[2];
    q1[(size_t)n * 2 + 1] = u[3];
}

// ---- gather pass (HALF=0/1): agg half = q_half[n] + sum q_half[src] + b1 half.
// 2 lanes/node x 16 B; srcs streamed nontemporal; q half is L2-resident (3.2 MB/XCD).
template <int HALF>
__global__ __launch_bounds__(256) void gather_half_kernel(const uint4* __restrict__ qh,
                                                          const int* __restrict__ srcs,
                                                          const int* __restrict__ off,
                                                          const float* __restrict__ b1,
                                                          float* __restrict__ agg) {
    int t = blockIdx.x * 256 + threadIdx.x;
    int n = t >> 1;
    if (n >= NN) return;
    int p = t & 1;
    float a[8];
    {   // self term
        uint4 v = qh[(size_t)n * 2 + p];
        a[0] = __uint_as_float(v.x << 16);
        a[1] = __uint_as_float(v.x & 0xffff0000u);
        a[2] = __uint_as_float(v.y << 16);
        a[3] = __uint_as_float(v.y & 0xffff0000u);
        a[4] = __uint_as_float(v.z << 16);
        a[5] = __uint_as_float(v.z & 0xffff0000u);
        a[6] = __uint_as_float(v.w << 16);
        a[7] = __uint_as_float(v.w & 0xffff0000u);
    }
    int o0 = off[n], o1 = off[n + 1];
    const int* lst = srcs + o0;
    int d = o1 - o0;
    int i = 0;
    for (; i + 4 <= d; i += 4) {
        int s0 = __builtin_nontemporal_load(lst + i);
        int s1 = __builtin_nontemporal_load(lst + i + 1);
        int s2 = __builtin_nontemporal_load(lst + i + 2);
        int s3 = __builtin_nontemporal_load(lst + i + 3);
        uint4 v0 = qh[(size_t)s0 * 2 + p];
        uint4 v1 = qh[(size_t)s1 * 2 + p];
        uint4 v2 = qh[(size_t)s2 * 2 + p];
        uint4 v3 = qh[(size_t)s3 * 2 + p];
#pragma unroll
        for (int w = 0; w < 4; w++) {
            unsigned ux = (w==0)?v0.x:(w==1)?v1.x:(w==2)?v2.x:v3.x;
            unsigned uy = (w==0)?v0.y:(w==1)?v1.y:(w==2)?v2.y:v3.y;
            unsigned uz = (w==0)?v0.z:(w==1)?v1.z:(w==2)?v2.z:v3.z;
            unsigned uw = (w==0)?v0.w:(w==1)?v1.w:(w==2)?v2.w:v3.w;
            a[0] += __uint_as_float(ux << 16);
            a[1] += __uint_as_float(ux & 0xffff0000u);
            a[2] += __uint_as_float(uy << 16);
            a[3] += __uint_as_float(uy & 0xffff0000u);
            a[4] += __uint_as_float(uz << 16);
            a[5] += __uint_as_float(uz & 0xffff0000u);
            a[6] += __uint_as_float(uw << 16);
            a[7] += __uint_as_float(uw & 0xffff0000u);
        }
    }
    for (; i < d; i++) {
        int s = __builtin_nontemporal_load(lst + i);
        uint4 v = qh[(size_t)s * 2 + p];
        a[0] += __uint_as_float(v.x << 16);
        a[1] += __uint_as_float(v.x & 0xffff0000u);
        a[2] += __uint_as_float(v.y << 16);
        a[3] += __uint_as_float(v.y & 0xffff0000u);
        a[4] += __uint_as_float(v.z << 16);
        a[5] += __uint_as_float(v.z & 0xffff0000u);
        a[6] += __uint_as_float(v.w << 16);
        a[7] += __uint_as_float(v.w & 0xffff0000u);
    }
    const float* bb = b1 + HALF * 16 + p * 8;
#pragma unroll
    for (int k = 0; k < 8; k++) a[k] += bb[k];
    float4* ar = (float4*)(agg + (size_t)n * 32 + HALF * 16 + p * 8);
    float4 f0, f1;
    f0.x = a[0]; f0.y = a[1]; f0.z = a[2]; f0.w = a[3];
    f1.x = a[4]; f1.y = a[5]; f1.z = a[6]; f1.w = a[7];
    ar[0] = f0; ar[1] = f1;
}

// ---- MLP tail: u = relu(agg); r = relu(u@w2 + b2); write h; accumulate BN stats.
__global__ __launch_bounds__(256) void mlp_kernel(const float* __restrict__ agg,
                                                  const float* __restrict__ w2,
                                                  const float* __restrict__ b2,
                                                  float* __restrict__ r,
                                                  float* __restrict__ stats) {
    __shared__ float tile[256 * 33];
    __shared__ float ps[8 * 32];
    __shared__ float pq[8 * 32];
    int tid = threadIdx.x;
    int n = blockIdx.x * 256 + tid;
    float rc[32];
    if (n < NN) {
        float u[32];
        const float4* a4 = (const float4*)(agg + (size_t)n * 32);
#pragma unroll
        for (int k = 0; k < 8; k++) {
            float4 v = a4[k];
            u[4*k]   = fmaxf(v.x, 0.f);
            u[4*k+1] = fmaxf(v.y, 0.f);
            u[4*k+2] = fmaxf(v.z, 0.f);
            u[4*k+3] = fmaxf(v.w, 0.f);
        }
#pragma unroll
        for (int c = 0; c < 32; c++) rc[c] = b2[c];
#pragma unroll 4
        for (int j = 0; j < 32; j++) {
            float uj = u[j];
            const float* wrow = w2 + (size_t)j * 32;
#pragma unroll
            for (int c = 0; c < 32; c++) rc[c] = fmaf(uj, wrow[c], rc[c]);
        }
#pragma unroll
        for (int c = 0; c < 32; c++) rc[c] = fmaxf(rc[c], 0.f);
        float4* rr = (float4*)(r + (size_t)n * 32);
#pragma unroll
        for (int k = 0; k < 8; k++) {
            float4 v; v.x = rc[4*k]; v.y = rc[4*k+1]; v.z = rc[4*k+2]; v.w = rc[4*k+3];
            rr[k] = v;
        }
    } else {
#pragma unroll
        for (int c = 0; c < 32; c++) rc[c] = 0.f;
    }
#pragma unroll
    for (int c = 0; c < 32; c++) tile[tid * 33 + c] = rc[c];
    __syncthreads();
    {
        int c = tid & 31, rb = tid >> 5;
        float s = 0.f, sq = 0.f;
        for (int it = 0; it < 32; it++) {
            float v = tile[(rb * 32 + it) * 33 + c];
            s += v; sq += v * v;
        }
        ps[rb * 32 + c] = s; pq[rb * 32 + c] = sq;
    }
    __syncthreads();
    if (tid < 32) {
        float s = 0.f, sq = 0.f;
#pragma unroll
        for (int rb = 0; rb < 8; rb++) { s += ps[rb * 32 + tid]; sq += pq[rb * 32 + tid]; }
        atomicAdd(&stats[tid], s);
        atomicAdd(&stats[32 + tid], sq);
    }
}

__global__ void bnfin_kernel(const float* __restrict__ stats, const float* __restrict__ g,
                             const float* __restrict__ be, float* __restrict__ bnab) {
    int c = threadIdx.x;
    if (c >= 32) return;
    float mean = stats[c] * (1.0f / NN);
    float var  = fmaxf(stats[32 + c] * (1.0f / NN) - mean * mean, 0.f);
    float a = g[c] * rsqrtf(var + 1e-5f);
    bnab[c] = a;
    bnab[32 + c] = be[c] - mean * a;
}

#define PR 128
__global__ __launch_bounds__(256) void pool_kernel(const float* __restrict__ h,
                                                   const int* __restrict__ batch,
                                                   float* __restrict__ pooled,
                                                   float* __restrict__ pcnt) {
    int t = blockIdx.x * 256 + threadIdx.x;
    int c = t & 31;
    int g = t >> 5;
    int r0 = g * PR;
    if (r0 >= NN) return;
    int r1 = min(r0 + PR, NN);
    int cur = batch[r0];
    float acc = 0.f, cn = 0.f;
    for (int rr = r0; rr < r1; rr++) {
        int b = batch[rr];
        if (b != cur) {
            atomicAdd(&pooled[cur * 32 + c], acc);
            if (c == 0) atomicAdd(&pcnt[cur], cn);
            acc = 0.f; cn = 0.f; cur = b;
        }
        acc += h[(size_t)rr * 32 + c];
        cn += 1.f;
    }
    atomicAdd(&pooled[cur * 32 + c], acc);
    if (c == 0) atomicAdd(&pcnt[cur], cn);
}

__global__ __launch_bounds__(128) void head_kernel(const float* __restrict__ pooled,
                                                   const float* __restrict__ pcnt,
                                                   const float* __restrict__ bnab,
                                                   const float* __restrict__ fc1w,
                                                   const float* __restrict__ fc1b,
                                                   const float* __restrict__ fc2w,
                                                   const float* __restrict__ fc2b,
                                                   float* __restrict__ out) {
    int g = threadIdx.x;
    if (g >= BB) return;
    float inv = 1.f / fmaxf(pcnt[g], 1.f);
    float xv[32];
#pragma unroll
    for (int c = 0; c < 32; c++) xv[c] = fmaf(bnab[c], pooled[g * 32 + c] * inv, bnab[32 + c]);
    float u[32];
#pragma unroll 4
    for (int k = 0; k < 32; k++) {
        float s = fc1b[k];
#pragma unroll
        for (int c = 0; c < 32; c++) s = fmaf(xv[c], fc1w[c * 32 + k], s);
        u[k] = fmaxf(s, 0.f);
    }
    float l[8];
#pragma unroll
    for (int o = 0; o < 8; o++) {
        float s = fc2b[o];
#pragma unroll
        for (int k = 0; k < 32; k++) s = fmaf(u[k], fc2w[k * 8 + o], s);
        l[o] = s;
    }
    float m = l[0];
#pragma unroll
    for (int o = 1; o < 8; o++) m = fmaxf(m, l[o]);
    float se = 0.f;
#pragma unroll
    for (int o = 0; o < 8; o++) se += expf(l[o] - m);
    float lse = logf(se) + m;
#pragma unroll
    for (int o = 0; o < 8; o++) out[g * 8 + o] = l[o] - lse;
}

extern "C" void kernel_launch(void* const* d_in, const int* in_sizes, int n_in,
                              void* d_out, int out_size, void* d_ws, size_t ws_size,
                              hipStream_t stream) {
    const float* x    = (const float*)d_in[0];
    const int*   ei   = (const int*)d_in[1];
    const int*   batch= (const int*)d_in[2];
    const float* w1_0 = (const float*)d_in[3];
    const float* b1_0 = (const float*)d_in[4];
    const float* w2_0 = (const float*)d_in[5];
    const float* b2_0 = (const float*)d_in[6];
    const float* g_0  = (const float*)d_in[7];
    const float* be_0 = (const float*)d_in[8];
    const float* w1s  = (const float*)d_in[9];
    const float* b1s  = (const float*)d_in[10];
    const float* w2s  = (const float*)d_in[11];
    const float* b2s  = (const float*)d_in[12];
    const float* gs   = (const float*)d_in[13];
    const float* bes  = (const float*)d_in[14];
    const float* fc1w = (const float*)d_in[15];
    const float* fc1b = (const float*)d_in[16];
    const float* fc2w = (const float*)d_in[17];
    const float* fc2b = (const float*)d_in[18];
    float* out = (float*)d_out;

    char* ws = (char*)d_ws;
    uint4*    q0    = (uint4*)(ws + Q0_OFF);
    uint4*    q1    = (uint4*)(ws + Q1_OFF);
    float*    agg   = (float*)(ws + AGG_OFF);
    float*    h     = (float*)(ws + H_OFF);
    int*      epack = (int*)(ws + EPACK_OFF);
    int*      srcs  = (int*)(ws + SRC_OFF);
    int*      off   = (int*)(ws + OFF_OFF);
    int*      hist  = (int*)(ws + HIST_OFF);
    int*      start = (int*)(ws + START_OFF);
    int*      bbase = (int*)(ws + BBASE_OFF);
    int*      tot   = (int*)(ws + TOT_OFF);
    float*    stats = (float*)(ws + STATS_OFF);
    float*    bnab  = (float*)(ws + BNAB_OFF);
    float*    pooled= (float*)(ws + POOLED_OFF);
    float*    pcnt  = (float*)(ws + PCNT_OFF);

    hipMemsetAsync(ws + ZERO_OFF, 0, ZERO_BYTES, stream);

    // CSR build chain
    hist_kernel<<<EBLK, 256, 0, stream>>>(ei, hist);
    totals_kernel<<<NB / 64, 64, 0, stream>>>(hist, tot);
    scan_kernel<<<1, NB, 0, stream>>>(tot, bbase);
    starts_kernel<<<NB / 128, 128, 0, stream>>>(hist, bbase, start);
    scatter_kernel<<<EBLK, 256, 0, stream>>>(ei, start, epack);
    csr_compact_kernel<<<NB, 256, 0, stream>>>(epack, bbase, off, srcs);

    const int nblk = (NN + 255) / 256;
    const int gblk = (NN * 2 + 255) / 256;

    // layer 0 (F_IN=128)
    proj_kernel<128><<<nblk, 256, 0, stream>>>(x, w1_0, nullptr, q0, q1, stats);
    gather_half_kernel<0><<<gblk, 256, 0, stream>>>(q0, srcs, off, b1_0, agg);
    gather_half_kernel<1><<<gblk, 256, 0, stream>>>(q1, srcs, off, b1_0, agg);
    mlp_kernel<<<nblk, 256, 0, stream>>>(agg, w2_0, b2_0, h, stats);
    bnfin_kernel<<<1, 64, 0, stream>>>(stats, g_0, be_0, bnab);

    // layers 1..3, prev BN folded into projection
    for (int i = 0; i < 3; i++) {
        proj_kernel<32><<<nblk, 256, 0, stream>>>(h, w1s + i * 1024, bnab, q0, q1, stats);
        gather_half_kernel<0><<<gblk, 256, 0, stream>>>(q0, srcs, off, b1s + i * 32, agg);
        gather_half_kernel<1><<<gblk, 256, 0, stream>>>(q1, srcs, off, b1s + i * 32, agg);
        mlp_kernel<<<nblk, 256, 0, stream>>>(agg, w2s + i * 1024, b2s + i * 32, h, stats);
        bnfin_kernel<<<1, 64, 0, stream>>>(stats, gs + i * 32, bes + i * 32, bnab);
    }

    int pthreads = ((NN + PR - 1) / PR) * 32;
    pool_kernel<<<(pthreads + 255) / 256, 256, 0, stream>>>(h, batch, pooled, pcnt);
    head_kernel<<<1, 128, 0, stream>>>(pooled, pcnt, bnab, fc1w, fc1b, fc2w, fc2b, out);
}

// Round 6
// 612.018 us; speedup vs baseline: 1.2802x; 1.2802x over previous
//
#include <hip/hip_runtime.h>
#include <hip/hip_bf16.h>

#define NN   100000
#define EE   3200000
#define HH   32
#define BB   128
#define KMAX 96
#define NBKT 256         // buckets
#define BSPAN 391        // ceil(NN/NBKT); bucket b covers dst in [b*391, ...)
#define WSPAN 98         // csr-build window within a bucket (4 windows/bucket)
#define EBLK 256         // edge-chunk blocks
#define CHUNK 12500      // EE / EBLK exactly

// ws layout (bytes), non-overlapping
static constexpr size_t Q_OFF      = 0;           // N*32 bf16 = 6.4 MB
static constexpr size_t AGG_OFF    = 6400000;     // N*32 f32 = 12.8 MB
static constexpr size_t H_OFF      = 19200000;    // N*32 f32 = 12.8 MB
static constexpr size_t EPACK_OFF  = 32000000;    // EE int = 12.8 MB
static constexpr size_t SRC_OFF    = 44800000;    // EE int = 12.8 MB compact csr
static constexpr size_t OFF_OFF    = 57600000;    // (N+1) int
static constexpr size_t HIST_OFF   = 58100000;    // EBLK*NBKT int = 256 KB
static constexpr size_t START_OFF  = 58400000;    // EBLK*NBKT int = 256 KB
static constexpr size_t BBASE_OFF  = 58700000;    // (NBKT+1) int
static constexpr size_t TOT_OFF    = 58710000;    // NBKT int
static constexpr size_t STATS_OFF  = 58720000;    // 64 f32
static constexpr size_t BNAB_OFF   = 58720256;    // 64 f32
static constexpr size_t POOLED_OFF = 58720512;    // B*32 f32
static constexpr size_t PCNT_OFF   = 58736896;    // B f32
static constexpr size_t ZERO_OFF   = POOLED_OFF;
static constexpr size_t ZERO_BYTES = 16896;

// ---- K1: per-block LDS histogram of dst buckets
__global__ __launch_bounds__(256) void hist_kernel(const int* __restrict__ ei,
                                                   int* __restrict__ hist) {
    __shared__ int lh[NBKT];
    int tid = threadIdx.x, blk = blockIdx.x;
    for (int i = tid; i < NBKT; i += 256) lh[i] = 0;
    __syncthreads();
    int e0 = blk * CHUNK;
    for (int e = e0 + tid; e < e0 + CHUNK; e += 256) {
        int d = ei[EE + e];
        atomicAdd(&lh[d / BSPAN], 1);
    }
    __syncthreads();
    for (int i = tid; i < NBKT; i += 256) hist[blk * NBKT + i] = lh[i];
}

// ---- K2a: bucket totals
__global__ __launch_bounds__(64) void totals_kernel(const int* __restrict__ hist,
                                                    int* __restrict__ tot) {
    int b = blockIdx.x * 64 + threadIdx.x;
    int s = 0;
    for (int blk = 0; blk < EBLK; blk++) s += hist[blk * NBKT + b];
    tot[b] = s;
}

// ---- K2b: exclusive scan of NBKT totals
__global__ __launch_bounds__(NBKT) void scan_kernel(const int* __restrict__ tot,
                                                    int* __restrict__ bbase) {
    __shared__ int sm[NBKT];
    int t = threadIdx.x;
    int mine = tot[t];
    sm[t] = mine;
    __syncthreads();
    for (int off = 1; off < NBKT; off <<= 1) {
        int v = (t >= off) ? sm[t - off] : 0;
        __syncthreads();
        sm[t] += v;
        __syncthreads();
    }
    bbase[t] = sm[t] - mine;
    if (t == NBKT - 1) bbase[NBKT] = sm[t];
}

// ---- K2c: per-(block,bucket) start offsets
__global__ __launch_bounds__(128) void starts_kernel(const int* __restrict__ hist,
                                                     const int* __restrict__ bbase,
                                                     int* __restrict__ start) {
    int b = blockIdx.x * 128 + threadIdx.x;
    int run = bbase[b];
    for (int blk = 0; blk < EBLK; blk++) {
        start[blk * NBKT + b] = run;
        run += hist[blk * NBKT + b];
    }
}

// ---- K3: scatter packed (src | dstoff<<17) into bucket-grouped array.
// 256 blocks x 256 buckets -> ~49-edge (196 B) runs, write amp ~1.3x.
__global__ __launch_bounds__(256) void scatter_kernel(const int* __restrict__ ei,
                                                      const int* __restrict__ start,
                                                      int* __restrict__ epack) {
    __shared__ int loff[NBKT];
    int tid = threadIdx.x, blk = blockIdx.x;
    for (int i = tid; i < NBKT; i += 256) loff[i] = start[blk * NBKT + i];
    __syncthreads();
    int e0 = blk * CHUNK;
    for (int e = e0 + tid; e < e0 + CHUNK; e += 256) {
        int s = ei[e];
        int d = ei[EE + e];
        int b = d / BSPAN;
        int slot = atomicAdd(&loff[b], 1);
        epack[slot] = s | ((d - b * BSPAN) << 17);
    }
}

// ---- K4: compact CSR build. 4 window-blocks per bucket; each scans the bucket's
// edges once, counts before-window edges for exact offsets, LDS-scatters its
// 98-node window, then writes off + dense srcs coalesced. Raw counts used for
// offsets (KMAX guard is LDS-safety only; P(deg>96) ~ 1e-20).
__global__ __launch_bounds__(256) void csr_compact_kernel(const int* __restrict__ epack,
                                                          const int* __restrict__ bbase,
                                                          int* __restrict__ off,
                                                          int* __restrict__ srcs) {
    __shared__ int lcnt[WSPAN];
    __shared__ int lbase[WSPAN + 1];
    __shared__ int lcsr[WSPAN * KMAX];   // 37632 B
    __shared__ int sh_before;
    int blk = blockIdx.x;
    int b = blk >> 2, w = blk & 3;
    int base = b * BSPAN;
    int span = NN - base;
    if (span <= 0) return;
    if (span > BSPAN) span = BSPAN;
    int wstart = w * WSPAN;
    if (wstart >= span) return;
    int wend = min(wstart + WSPAN, span);
    int wn = wend - wstart;
    int tid = threadIdx.x;
    if (tid == 0) sh_before = 0;
    for (int i = tid; i < wn; i += 256) lcnt[i] = 0;
    __syncthreads();
    int p0 = bbase[b], p1 = bbase[b + 1];
    int nbefore = 0;
    for (int i = p0 + tid; i < p1; i += 256) {
        int wd = epack[i];
        int ld = wd >> 17;
        if (ld < wstart) nbefore++;
        else if (ld < wend) {
            int slot = atomicAdd(&lcnt[ld - wstart], 1);
            if (slot < KMAX) lcsr[(ld - wstart) * KMAX + slot] = wd & 0x1FFFF;
        }
    }
    atomicAdd(&sh_before, nbefore);
    __syncthreads();
    if (tid == 0) {
        int run = 0;
        for (int i = 0; i < wn; i++) { lbase[i] = run; run += lcnt[i]; }
        lbase[wn] = run;
    }
    __syncthreads();
    int w0 = p0 + sh_before;
    for (int i = tid; i < wn; i += 256) off[base + wstart + i] = w0 + lbase[i];
    if (base + wend == NN && tid == 0) off[NN] = w0 + lbase[wn];
    int m = lbase[wn];
    for (int j = tid; j < m; j += 256) {
        int lo = 0, hi = wn - 1;
        while (lo < hi) {
            int mid = (lo + hi + 1) >> 1;
            if (lbase[mid] <= j) lo = mid; else hi = mid - 1;
        }
        int sl = j - lbase[lo]; if (sl >= KMAX) sl = KMAX - 1;
        srcs[w0 + j] = lcsr[lo * KMAX + sl];
    }
}

__device__ __forceinline__ unsigned bf16rn(float f) {
    unsigned b = __float_as_uint(f);
    return (b + 0x7fffu + ((b >> 16) & 1u)) >> 16;   // RNE
}

__device__ __forceinline__ void acc_row(float* a, uint4 v) {
    a[0] += __uint_as_float(v.x << 16);
    a[1] += __uint_as_float(v.x & 0xffff0000u);
    a[2] += __uint_as_float(v.y << 16);
    a[3] += __uint_as_float(v.y & 0xffff0000u);
    a[4] += __uint_as_float(v.z << 16);
    a[5] += __uint_as_float(v.z & 0xffff0000u);
    a[6] += __uint_as_float(v.w << 16);
    a[7] += __uint_as_float(v.w & 0xffff0000u);
}

// ---- projection q(bf16, 64 B rows) = h @ w1. FIN==32 folds prev BN affine.
template <int FIN>
__global__ __launch_bounds__(256) void proj_kernel(const float* __restrict__ hin,
                                                   const float* __restrict__ w1,
                                                   const float* __restrict__ bnab,
                                                   uint4* __restrict__ q4,
                                                   float* __restrict__ stats) {
    int tid = threadIdx.x;
    if (blockIdx.x == 0 && tid < 64) stats[tid] = 0.f;
    int n = blockIdx.x * 256 + tid;
    if (n >= NN) return;
    float acc[32];
#pragma unroll
    for (int c = 0; c < 32; c++) acc[c] = 0.f;
    const float4* h4 = (const float4*)(hin + (size_t)n * FIN);
    for (int jj = 0; jj < FIN; jj += 32) {
        float hv[32];
#pragma unroll
        for (int k = 0; k < 8; k++) {
            float4 v = h4[jj / 4 + k];
            hv[4 * k] = v.x; hv[4 * k + 1] = v.y; hv[4 * k + 2] = v.z; hv[4 * k + 3] = v.w;
        }
        if constexpr (FIN == 32) {
#pragma unroll
            for (int j = 0; j < 32; j++) hv[j] = fmaf(hv[j], bnab[j], bnab[32 + j]);
        }
#pragma unroll 4
        for (int j = 0; j < 32; j++) {
            float hvj = hv[j];
            const float* wrow = w1 + (size_t)(jj + j) * 32;
#pragma unroll
            for (int c = 0; c < 32; c++) acc[c] = fmaf(hvj, wrow[c], acc[c]);
        }
    }
#pragma unroll
    for (int k = 0; k < 4; k++) {
        uint4 u;
        u.x = bf16rn(acc[8*k+0]) | (bf16rn(acc[8*k+1]) << 16);
        u.y = bf16rn(acc[8*k+2]) | (bf16rn(acc[8*k+3]) << 16);
        u.z = bf16rn(acc[8*k+4]) | (bf16rn(acc[8*k+5]) << 16);
        u.w = bf16rn(acc[8*k+6]) | (bf16rn(acc[8*k+7]) << 16);
        q4[(size_t)n * 4 + k] = u;
    }
}

// ---- gather: agg[n] = q[n] + sum q[src] + b1. 4 lanes/node x 16 B, 8-unrolled
// (32 lines in flight per node). srcs streamed nontemporal.
__global__ __launch_bounds__(256) void gather_kernel(const uint4* __restrict__ q4,
                                                     const int* __restrict__ srcs,
                                                     const int* __restrict__ off,
                                                     const float* __restrict__ b1,
                                                     float* __restrict__ agg) {
    int t = blockIdx.x * 256 + threadIdx.x;
    int n = t >> 2;
    if (n >= NN) return;
    int p = t & 3;
    float a[8];
#pragma unroll
    for (int k = 0; k < 8; k++) a[k] = b1[p * 8 + k];
    acc_row(a, q4[(size_t)n * 4 + p]);   // self term
    int o0 = off[n], o1 = off[n + 1];
    const int* lst = srcs + o0;
    int d = o1 - o0;
    int i = 0;
    for (; i + 8 <= d; i += 8) {
        int s0 = __builtin_nontemporal_load(lst + i);
        int s1 = __builtin_nontemporal_load(lst + i + 1);
        int s2 = __builtin_nontemporal_load(lst + i + 2);
        int s3 = __builtin_nontemporal_load(lst + i + 3);
        int s4 = __builtin_nontemporal_load(lst + i + 4);
        int s5 = __builtin_nontemporal_load(lst + i + 5);
        int s6 = __builtin_nontemporal_load(lst + i + 6);
        int s7 = __builtin_nontemporal_load(lst + i + 7);
        uint4 v0 = q4[(size_t)s0 * 4 + p];
        uint4 v1 = q4[(size_t)s1 * 4 + p];
        uint4 v2 = q4[(size_t)s2 * 4 + p];
        uint4 v3 = q4[(size_t)s3 * 4 + p];
        uint4 v4 = q4[(size_t)s4 * 4 + p];
        uint4 v5 = q4[(size_t)s5 * 4 + p];
        uint4 v6 = q4[(size_t)s6 * 4 + p];
        uint4 v7 = q4[(size_t)s7 * 4 + p];
        acc_row(a, v0); acc_row(a, v1); acc_row(a, v2); acc_row(a, v3);
        acc_row(a, v4); acc_row(a, v5); acc_row(a, v6); acc_row(a, v7);
    }
    for (; i < d; i++) {
        int s = __builtin_nontemporal_load(lst + i);
        acc_row(a, q4[(size_t)s * 4 + p]);
    }
    float4* ar = (float4*)(agg + (size_t)n * 32 + p * 8);
    float4 f0, f1;
    f0.x = a[0]; f0.y = a[1]; f0.z = a[2]; f0.w = a[3];
    f1.x = a[4]; f1.y = a[5]; f1.z = a[6]; f1.w = a[7];
    ar[0] = f0; ar[1] = f1;
}

// ---- MLP tail: u = relu(agg); r = relu(u@w2 + b2); write h; accumulate BN stats.
__global__ __launch_bounds__(256) void mlp_kernel(const float* __restrict__ agg,
                                                  const float* __restrict__ w2,
                                                  const float* __restrict__ b2,
                                                  float* __restrict__ r,
                                                  float* __restrict__ stats) {
    __shared__ float tile[256 * 33];
    __shared__ float ps[8 * 32];
    __shared__ float pq[8 * 32];
    int tid = threadIdx.x;
    int n = blockIdx.x * 256 + tid;
    float rc[32];
    if (n < NN) {
        float u[32];
        const float4* a4 = (const float4*)(agg + (size_t)n * 32);
#pragma unroll
        for (int k = 0; k < 8; k++) {
            float4 v = a4[k];
            u[4*k]   = fmaxf(v.x, 0.f);
            u[4*k+1] = fmaxf(v.y, 0.f);
            u[4*k+2] = fmaxf(v.z, 0.f);
            u[4*k+3] = fmaxf(v.w, 0.f);
        }
#pragma unroll
        for (int c = 0; c < 32; c++) rc[c] = b2[c];
#pragma unroll 4
        for (int j = 0; j < 32; j++) {
            float uj = u[j];
            const float* wrow = w2 + (size_t)j * 32;
#pragma unroll
            for (int c = 0; c < 32; c++) rc[c] = fmaf(uj, wrow[c], rc[c]);
        }
#pragma unroll
        for (int c = 0; c < 32; c++) rc[c] = fmaxf(rc[c], 0.f);
        float4* rr = (float4*)(r + (size_t)n * 32);
#pragma unroll
        for (int k = 0; k < 8; k++) {
            float4 v; v.x = rc[4*k]; v.y = rc[4*k+1]; v.z = rc[4*k+2]; v.w = rc[4*k+3];
            rr[k] = v;
        }
    } else {
#pragma unroll
        for (int c = 0; c < 32; c++) rc[c] = 0.f;
    }
#pragma unroll
    for (int c = 0; c < 32; c++) tile[tid * 33 + c] = rc[c];
    __syncthreads();
    {
        int c = tid & 31, rb = tid >> 5;
        float s = 0.f, sq = 0.f;
        for (int it = 0; it < 32; it++) {
            float v = tile[(rb * 32 + it) * 33 + c];
            s += v; sq += v * v;
        }
        ps[rb * 32 + c] = s; pq[rb * 32 + c] = sq;
    }
    __syncthreads();
    if (tid < 32) {
        float s = 0.f, sq = 0.f;
#pragma unroll
        for (int rb = 0; rb < 8; rb++) { s += ps[rb * 32 + tid]; sq += pq[rb * 32 + tid]; }
        atomicAdd(&stats[tid], s);
        atomicAdd(&stats[32 + tid], sq);
    }
}

__global__ void bnfin_kernel(const float* __restrict__ stats, const float* __restrict__ g,
                             const float* __restrict__ be, float* __restrict__ bnab) {
    int c = threadIdx.x;
    if (c >= 32) return;
    float mean = stats[c] * (1.0f / NN);
    float var  = fmaxf(stats[32 + c] * (1.0f / NN) - mean * mean, 0.f);
    float a = g[c] * rsqrtf(var + 1e-5f);
    bnab[c] = a;
    bnab[32 + c] = be[c] - mean * a;
}

// ---- pooling: PR=16 -> 6250 groups x 32 lanes = 782 blocks (was 98: latency-bound)
#define PR 16
__global__ __launch_bounds__(256) void pool_kernel(const float* __restrict__ h,
                                                   const int* __restrict__ batch,
                                                   float* __restrict__ pooled,
                                                   float* __restrict__ pcnt) {
    int t = blockIdx.x * 256 + threadIdx.x;
    int c = t & 31;
    int g = t >> 5;
    int r0 = g * PR;
    if (r0 >= NN) return;
    int r1 = min(r0 + PR, NN);
    int cur = batch[r0];
    float acc = 0.f, cn = 0.f;
    for (int rr = r0; rr < r1; rr++) {
        int b = batch[rr];
        if (b != cur) {
            atomicAdd(&pooled[cur * 32 + c], acc);
            if (c == 0) atomicAdd(&pcnt[cur], cn);
            acc = 0.f; cn = 0.f; cur = b;
        }
        acc += h[(size_t)rr * 32 + c];
        cn += 1.f;
    }
    atomicAdd(&pooled[cur * 32 + c], acc);
    if (c == 0) atomicAdd(&pcnt[cur], cn);
}

__global__ __launch_bounds__(128) void head_kernel(const float* __restrict__ pooled,
                                                   const float* __restrict__ pcnt,
                                                   const float* __restrict__ bnab,
                                                   const float* __restrict__ fc1w,
                                                   const float* __restrict__ fc1b,
                                                   const float* __restrict__ fc2w,
                                                   const float* __restrict__ fc2b,
                                                   float* __restrict__ out) {
    int g = threadIdx.x;
    if (g >= BB) return;
    float inv = 1.f / fmaxf(pcnt[g], 1.f);
    float xv[32];
#pragma unroll
    for (int c = 0; c < 32; c++) xv[c] = fmaf(bnab[c], pooled[g * 32 + c] * inv, bnab[32 + c]);
    float u[32];
#pragma unroll 4
    for (int k = 0; k < 32; k++) {
        float s = fc1b[k];
#pragma unroll
        for (int c = 0; c < 32; c++) s = fmaf(xv[c], fc1w[c * 32 + k], s);
        u[k] = fmaxf(s, 0.f);
    }
    float l[8];
#pragma unroll
    for (int o = 0; o < 8; o++) {
        float s = fc2b[o];
#pragma unroll
        for (int k = 0; k < 32; k++) s = fmaf(u[k], fc2w[k * 8 + o], s);
        l[o] = s;
    }
    float m = l[0];
#pragma unroll
    for (int o = 1; o < 8; o++) m = fmaxf(m, l[o]);
    float se = 0.f;
#pragma unroll
    for (int o = 0; o < 8; o++) se += expf(l[o] - m);
    float lse = logf(se) + m;
#pragma unroll
    for (int o = 0; o < 8; o++) out[g * 8 + o] = l[o] - lse;
}

extern "C" void kernel_launch(void* const* d_in, const int* in_sizes, int n_in,
                              void* d_out, int out_size, void* d_ws, size_t ws_size,
                              hipStream_t stream) {
    const float* x    = (const float*)d_in[0];
    const int*   ei   = (const int*)d_in[1];
    const int*   batch= (const int*)d_in[2];
    const float* w1_0 = (const float*)d_in[3];
    const float* b1_0 = (const float*)d_in[4];
    const float* w2_0 = (const float*)d_in[5];
    const float* b2_0 = (const float*)d_in[6];
    const float* g_0  = (const float*)d_in[7];
    const float* be_0 = (const float*)d_in[8];
    const float* w1s  = (const float*)d_in[9];
    const float* b1s  = (const float*)d_in[10];
    const float* w2s  = (const float*)d_in[11];
    const float* b2s  = (const float*)d_in[12];
    const float* gs   = (const float*)d_in[13];
    const float* bes  = (const float*)d_in[14];
    const float* fc1w = (const float*)d_in[15];
    const float* fc1b = (const float*)d_in[16];
    const float* fc2w = (const float*)d_in[17];
    const float* fc2b = (const float*)d_in[18];
    float* out = (float*)d_out;

    char* ws = (char*)d_ws;
    uint4*    q4    = (uint4*)(ws + Q_OFF);
    float*    agg   = (float*)(ws + AGG_OFF);
    float*    h     = (float*)(ws + H_OFF);
    int*      epack = (int*)(ws + EPACK_OFF);
    int*      srcs  = (int*)(ws + SRC_OFF);
    int*      off   = (int*)(ws + OFF_OFF);
    int*      hist  = (int*)(ws + HIST_OFF);
    int*      start = (int*)(ws + START_OFF);
    int*      bbase = (int*)(ws + BBASE_OFF);
    int*      tot   = (int*)(ws + TOT_OFF);
    float*    stats = (float*)(ws + STATS_OFF);
    float*    bnab  = (float*)(ws + BNAB_OFF);
    float*    pooled= (float*)(ws + POOLED_OFF);
    float*    pcnt  = (float*)(ws + PCNT_OFF);

    hipMemsetAsync(ws + ZERO_OFF, 0, ZERO_BYTES, stream);

    // CSR build chain
    hist_kernel<<<EBLK, 256, 0, stream>>>(ei, hist);
    totals_kernel<<<NBKT / 64, 64, 0, stream>>>(hist, tot);
    scan_kernel<<<1, NBKT, 0, stream>>>(tot, bbase);
    starts_kernel<<<NBKT / 128, 128, 0, stream>>>(hist, bbase, start);
    scatter_kernel<<<EBLK, 256, 0, stream>>>(ei, start, epack);
    csr_compact_kernel<<<NBKT * 4, 256, 0, stream>>>(epack, bbase, off, srcs);

    const int nblk = (NN + 255) / 256;
    const int gblk = (NN * 4 + 255) / 256;

    // layer 0 (F_IN=128)
    proj_kernel<128><<<nblk, 256, 0, stream>>>(x, w1_0, nullptr, q4, stats);
    gather_kernel<<<gblk, 256, 0, stream>>>(q4, srcs, off, b1_0, agg);
    mlp_kernel<<<nblk, 256, 0, stream>>>(agg, w2_0, b2_0, h, stats);
    bnfin_kernel<<<1, 64, 0, stream>>>(stats, g_0, be_0, bnab);

    // layers 1..3, prev BN folded into projection
    for (int i = 0; i < 3; i++) {
        proj_kernel<32><<<nblk, 256, 0, stream>>>(h, w1s + i * 1024, bnab, q4, stats);
        gather_kernel<<<gblk, 256, 0, stream>>>(q4, srcs, off, b1s + i * 32, agg);
        mlp_kernel<<<nblk, 256, 0, stream>>>(agg, w2s + i * 1024, b2s + i * 32, h, stats);
        bnfin_kernel<<<1, 64, 0, stream>>>(stats, gs + i * 32, bes + i * 32, bnab);
    }

    int pthreads = ((NN + PR - 1) / PR) * 32;
    pool_kernel<<<(pthreads + 255) / 256, 256, 0, stream>>>(h, batch, pooled, pcnt);
    head_kernel<<<1, 128, 0, stream>>>(pooled, pcnt, bnab, fc1w, fc1b, fc2w, fc2b, out);
}